// Round 1
// baseline (1029.211 us; speedup 1.0000x reference)
//
#include <hip/hip_runtime.h>
#include <hip/hip_bf16.h>
#include <math.h>

#define B_   16
#define D_   192
#define TX_  512
#define TY_  2048
#define NEGV (-1e9f)

// -------- workspace layout (bytes) --------
// S   : B*D*TX f32   @ 0          (6,291,456)
// MS  : B*D*TX f32   @ 6291456    (6,291,456)
// Cc  : B*TX   f32   @ 12582912   (32,768)
// NC  : B*TY*TX f32  @ 12615680   (67,108,864)
// dirs: B*2048*64 u8 @ 79724544   (2,097,152)   bit x of row y-1 at byte (y-1)*64 + (x>>3), bit (x&7)
// path: B*TY  i32    @ 81821696   (131,072)
// total ~82 MB

// -------- output layout (f32 elements) --------
// out_main [B,384,TY] @ 0          (12,582,912)
// l_length [B]        @ 12582912   (16)
// attn [B,TY,TX]      @ 12582928   (16,777,216)

// ============ Kernel A: per-(b,x) precompute ============
__global__ __launch_bounds__(512) void precomp(const float* __restrict__ xm,
                                               const float* __restrict__ xl,
                                               float* __restrict__ S,
                                               float* __restrict__ MS,
                                               float* __restrict__ Cc) {
    int b = blockIdx.x;
    int x = threadIdx.x;
    const float* mb = xm + (size_t)b * D_ * TX_;
    const float* lb = xl + (size_t)b * D_ * TX_;
    float* Sb  = S  + (size_t)b * D_ * TX_;
    float* MSb = MS + (size_t)b * D_ * TX_;
    float c = 0.f;
    for (int d = 0; d < D_; d++) {
        float lg = lb[d * TX_ + x];
        float mn = mb[d * TX_ + x];
        float s  = expf(-2.f * lg);
        float ms = mn * s;
        Sb[d * TX_ + x]  = s;
        MSb[d * TX_ + x] = ms;
        c += -0.9189385332046727f - lg - 0.5f * mn * mn * s;   // nc1 + nc4 terms
    }
    Cc[b * TX_ + x] = c;
}

// ============ Kernel B: NC = A(z) * B(s,ms) + c, f32 tiled GEMM ============
// 64x64 tile, 256 threads, 4x4 microtile, K-chunks of 16 over D.
__global__ __launch_bounds__(256) void gemm_nc(const float* __restrict__ z,
                                               const float* __restrict__ S,
                                               const float* __restrict__ MS,
                                               const float* __restrict__ Cc,
                                               float* __restrict__ NC) {
    int bx = blockIdx.x;            // 8  -> x tiles
    int by = blockIdx.y;            // 32 -> y tiles
    int b  = blockIdx.z;            // 16
    int tid = threadIdx.x;
    int tx_ = tid & 15, ty_ = tid >> 4;
    __shared__ __align__(16) float Zt[16][68];
    __shared__ __align__(16) float St[16][68];
    __shared__ __align__(16) float MSt[16][68];
    float acc[4][4];
#pragma unroll
    for (int i = 0; i < 4; i++)
#pragma unroll
        for (int j = 0; j < 4; j++) acc[i][j] = 0.f;

    int x0 = bx * 64, y0 = by * 64;
    const float* zb  = z  + (size_t)b * D_ * TY_;
    const float* Sb  = S  + (size_t)b * D_ * TX_;
    const float* MSb = MS + (size_t)b * D_ * TX_;

    for (int k0 = 0; k0 < D_; k0 += 16) {
#pragma unroll
        for (int e = tid; e < 1024; e += 256) {
            int kk = e >> 6, ee = e & 63;
            Zt[kk][ee]  = zb[(size_t)(k0 + kk) * TY_ + y0 + ee];
            St[kk][ee]  = Sb[(size_t)(k0 + kk) * TX_ + x0 + ee];
            MSt[kk][ee] = MSb[(size_t)(k0 + kk) * TX_ + x0 + ee];
        }
        __syncthreads();
#pragma unroll
        for (int kk = 0; kk < 16; kk++) {
            float4 zz = *(const float4*)&Zt[kk][ty_ * 4];
            float4 ss = *(const float4*)&St[kk][tx_ * 4];
            float4 mm = *(const float4*)&MSt[kk][tx_ * 4];
            float zA[4] = {zz.x, zz.y, zz.z, zz.w};
            float sA[4] = {ss.x, ss.y, ss.z, ss.w};
            float mA[4] = {mm.x, mm.y, mm.z, mm.w};
#pragma unroll
            for (int i = 0; i < 4; i++) {
                float u = -0.5f * zA[i] * zA[i];
#pragma unroll
                for (int j = 0; j < 4; j++) {
                    acc[i][j] += u * sA[j] + zA[i] * mA[j];
                }
            }
        }
        __syncthreads();
    }

    const float* cb = Cc + b * TX_ + x0 + tx_ * 4;
    float4 cc = *(const float4*)cb;
    float cA[4] = {cc.x, cc.y, cc.z, cc.w};
#pragma unroll
    for (int i = 0; i < 4; i++) {
        int y = y0 + ty_ * 4 + i;
        float4 o;
        o.x = acc[i][0] + cA[0];
        o.y = acc[i][1] + cA[1];
        o.z = acc[i][2] + cA[2];
        o.w = acc[i][3] + cA[3];
        *(float4*)&NC[((size_t)b * TY_ + y) * TX_ + x0 + tx_ * 4] = o;
    }
}

// ============ Kernel C: MAS forward DP (one wave per sample) ============
// lane holds x = lane*8 .. lane*8+7.  dirs bit = (v_diag > v_prev).
__global__ __launch_bounds__(64) void mas_forward(const float* __restrict__ NC,
                                                  unsigned char* __restrict__ dirs) {
    int b = blockIdx.x;
    int lane = threadIdx.x;
    const float* ncb = NC + (size_t)b * TY_ * TX_;
    const float4* nc4 = (const float4*)ncb;     // row y -> y*128 + lane*2

    float v[8];
#pragma unroll
    for (int j = 0; j < 8; j++) v[j] = NEGV;
    float nc00 = ncb[0];
    if (lane == 0) v[0] = nc00;

    // prefetch ring: 8 rows deep
    float4 buf[8][2];
#pragma unroll
    for (int p = 0; p < 8; p++) {
        buf[p][0] = nc4[(size_t)(1 + p) * 128 + lane * 2];
        buf[p][1] = nc4[(size_t)(1 + p) * 128 + lane * 2 + 1];
    }
    unsigned char* db = dirs + (size_t)b * 2048 * 64 + lane;

    for (int y0 = 1; y0 < 2048; y0 += 8) {
#pragma unroll
        for (int p = 0; p < 8; p++) {
            int y = y0 + p;
            if (y >= 2048) continue;         // uniform (last chunk only)
            float4 a = buf[p][0], c = buf[p][1];
            int yn = y + 8;
            if (yn < 2048) {
                buf[p][0] = nc4[(size_t)yn * 128 + lane * 2];
                buf[p][1] = nc4[(size_t)yn * 128 + lane * 2 + 1];
            }
            float ncv[8] = {a.x, a.y, a.z, a.w, c.x, c.y, c.z, c.w};
            float bound = __shfl_up(v[7], 1);
            bound = (lane == 0) ? NEGV : bound;
            unsigned bits = 0;
            float carry = bound;
#pragma unroll
            for (int j = 0; j < 8; j++) {
                float vp = v[j];
                float vd = carry;
                carry = vp;
                bits |= ((vd > vp) ? 1u : 0u) << j;
                v[j] = ncv[j] + fmaxf(vp, vd);
            }
            if (y < 520) {                   // mask x > y (only matters while y < 512+8)
                int xb = lane * 8;
#pragma unroll
                for (int j = 0; j < 8; j++)
                    if (xb + j > y) v[j] = NEGV;
            }
            db[(size_t)(y - 1) * 64] = (unsigned char)bits;
        }
    }
}

// ============ Kernel D: backtrack (one wave per sample, shfl-windowed) ============
__global__ __launch_bounds__(64) void mas_backtrack(const unsigned* __restrict__ dirs,
                                                    int* __restrict__ path) {
    int b = blockIdx.x;
    int lane = threadIdx.x;
    const unsigned* db = dirs + (size_t)b * 2048 * 16;   // 16 dwords per row
    int idx = TX_ - 1;                                   // path[2047]

    for (int y_hi = 2047; y_hi >= 1; y_hi -= 64) {
        int wb = (idx >> 5) - 2;
        if (wb < 0) wb = 0;
        int base = wb << 5;
        int y = y_hi - lane;
        unsigned w0 = 0, w1 = 0, w2 = 0;
        if (y >= 1) {
            const unsigned* r = db + (size_t)(y - 1) * 16 + wb;
            w0 = r[0]; w1 = r[1]; w2 = r[2];
        }
        int steps = (y_hi < 64) ? y_hi : 64;
        int my_path = 0;
#pragma unroll 8
        for (int t = 0; t < steps; t++) {
            if (lane == t) my_path = idx;
            unsigned u0 = (unsigned)__shfl((int)w0, t);
            unsigned u1 = (unsigned)__shfl((int)w1, t);
            unsigned u2 = (unsigned)__shfl((int)w2, t);
            int off = idx - base;
            unsigned w = (off < 32) ? u0 : ((off < 64) ? u1 : u2);
            idx -= (int)((w >> (off & 31)) & 1u);
        }
        if (lane < steps) path[b * TY_ + (y_hi - lane)] = my_path;
    }
    if (lane == 0) path[b * TY_ + 0] = idx;
}

// ============ Kernel E: durations + l_length ============
__global__ __launch_bounds__(512) void durations_ll(const int* __restrict__ path,
                                                    const float* __restrict__ logw,
                                                    float* __restrict__ out_l) {
    int b = blockIdx.x;
    int tid = threadIdx.x;
    __shared__ int wcnt[TX_];
    __shared__ float partial[8];
    wcnt[tid] = 0;
    __syncthreads();
    for (int y = tid; y < TY_; y += 512)
        atomicAdd(&wcnt[path[b * TY_ + y]], 1);
    __syncthreads();
    float t = logw[b * TX_ + tid] - logf((float)wcnt[tid] + 1e-6f);
    float sq = t * t;
#pragma unroll
    for (int off = 32; off > 0; off >>= 1) sq += __shfl_down(sq, off);
    if ((tid & 63) == 0) partial[tid >> 6] = sq;
    __syncthreads();
    if (tid == 0) {
        float s = 0.f;
#pragma unroll
        for (int i = 0; i < 8; i++) s += partial[i];
        out_l[b] = s;
    }
}

// ============ Kernel F: gather out_main ============
__global__ __launch_bounds__(256) void gather_main(const int* __restrict__ path,
                                                   const float* __restrict__ xm,
                                                   const float* __restrict__ xl,
                                                   float* __restrict__ out) {
    int c = blockIdx.x;      // 0..383
    int b = blockIdx.y;      // 0..15
    int tid = threadIdx.x;
    const float* src = (c < D_) ? (xm + ((size_t)b * D_ + c) * TX_)
                                : (xl + ((size_t)b * D_ + (c - D_)) * TX_);
    const int* pb = path + b * TY_;
    float* ob = out + ((size_t)b * 2 * D_ + c) * TY_;
#pragma unroll
    for (int k = 0; k < 8; k++) {
        int y = tid + k * 256;
        ob[y] = src[pb[y]];
    }
}

// ============ Kernel G: write one-hot attn ============
__global__ __launch_bounds__(128) void write_attn(const int* __restrict__ path,
                                                  float* __restrict__ attn) {
    int blk = blockIdx.x;            // b*2048 + y
    int b = blk >> 11;
    int y = blk & 2047;
    int tid = threadIdx.x;           // covers x in [4*tid, 4*tid+4)
    int p = path[b * TY_ + y];
    float4 val = make_float4(0.f, 0.f, 0.f, 0.f);
    if ((p >> 2) == tid) {
        int r = p & 3;
        if (r == 0) val.x = 1.f;
        else if (r == 1) val.y = 1.f;
        else if (r == 2) val.z = 1.f;
        else val.w = 1.f;
    }
    ((float4*)attn)[((size_t)blk) * 128 + tid] = val;
}

extern "C" void kernel_launch(void* const* d_in, const int* in_sizes, int n_in,
                              void* d_out, int out_size, void* d_ws, size_t ws_size,
                              hipStream_t stream) {
    const float* x_mean = (const float*)d_in[0];
    const float* x_logs = (const float*)d_in[1];
    const float* z      = (const float*)d_in[2];
    const float* logw   = (const float*)d_in[3];
    float* out = (float*)d_out;

    char* ws = (char*)d_ws;
    float* S            = (float*)(ws + 0);
    float* MS           = (float*)(ws + 6291456);
    float* Cc           = (float*)(ws + 12582912);
    float* NC           = (float*)(ws + 12615680);
    unsigned char* dirs = (unsigned char*)(ws + 79724544);
    int* path           = (int*)(ws + 81821696);

    float* out_main = out;                 // [B,384,TY]
    float* out_l    = out + 12582912;      // [B]
    float* out_attn = out + 12582928;      // [B,TY,TX]

    precomp<<<dim3(B_), dim3(512), 0, stream>>>(x_mean, x_logs, S, MS, Cc);
    gemm_nc<<<dim3(8, 32, 16), dim3(256), 0, stream>>>(z, S, MS, Cc, NC);
    mas_forward<<<dim3(B_), dim3(64), 0, stream>>>(NC, dirs);
    mas_backtrack<<<dim3(B_), dim3(64), 0, stream>>>((const unsigned*)dirs, path);
    durations_ll<<<dim3(B_), dim3(512), 0, stream>>>(path, logw, out_l);
    gather_main<<<dim3(384, 16), dim3(256), 0, stream>>>(path, x_mean, x_logs, out_main);
    write_attn<<<dim3(B_ * TY_), dim3(128), 0, stream>>>(path, out_attn);
}

// Round 2
// 1014.762 us; speedup vs baseline: 1.0142x; 1.0142x over previous
//
#include <hip/hip_runtime.h>
#include <hip/hip_bf16.h>
#include <math.h>

#define B_   16
#define D_   192
#define TX_  512
#define TY_  2048
#define NEGV (-1e9f)

// -------- workspace layout (bytes) --------
// S   : B*D*TX f32   @ 0          (6,291,456)
// MS  : B*D*TX f32   @ 6291456    (6,291,456)
// Cc  : B*TX   f32   @ 12582912   (32,768)
// NC  : B*TY*TX f32  @ 12615680   (67,108,864)
// dirs: B*2048*64 u8 @ 79724544   (2,097,152)
// path: B*TY  i32    @ 81821696   (131,072)

// -------- output layout (f32 elements) --------
// out_main [B,384,TY] @ 0, l_length [B] @ 12582912, attn [B,TY,TX] @ 12582928

typedef __attribute__((address_space(1))) const float glob_f;
typedef __attribute__((address_space(3))) float       lds_f;

// ============ Kernel A: per-(b,x) precompute ============
__global__ __launch_bounds__(512) void precomp(const float* __restrict__ xm,
                                               const float* __restrict__ xl,
                                               float* __restrict__ S,
                                               float* __restrict__ MS,
                                               float* __restrict__ Cc) {
    int b = blockIdx.x;
    int x = threadIdx.x;
    const float* mb = xm + (size_t)b * D_ * TX_;
    const float* lb = xl + (size_t)b * D_ * TX_;
    float* Sb  = S  + (size_t)b * D_ * TX_;
    float* MSb = MS + (size_t)b * D_ * TX_;
    float c = 0.f;
    for (int d = 0; d < D_; d++) {
        float lg = lb[d * TX_ + x];
        float mn = mb[d * TX_ + x];
        float s  = expf(-2.f * lg);
        float ms = mn * s;
        Sb[d * TX_ + x]  = s;
        MSb[d * TX_ + x] = ms;
        c += -0.9189385332046727f - lg - 0.5f * mn * mn * s;   // nc1 + nc4 terms
    }
    Cc[b * TX_ + x] = c;
}

// ============ Kernel B: NC = A(z) * B(s,ms) + c, f32 tiled GEMM ============
__global__ __launch_bounds__(256) void gemm_nc(const float* __restrict__ z,
                                               const float* __restrict__ S,
                                               const float* __restrict__ MS,
                                               const float* __restrict__ Cc,
                                               float* __restrict__ NC) {
    int bx = blockIdx.x;            // 8  -> x tiles
    int by = blockIdx.y;            // 32 -> y tiles
    int b  = blockIdx.z;            // 16
    int tid = threadIdx.x;
    int tx_ = tid & 15, ty_ = tid >> 4;
    __shared__ __align__(16) float Zt[16][68];
    __shared__ __align__(16) float St[16][68];
    __shared__ __align__(16) float MSt[16][68];
    float acc[4][4];
#pragma unroll
    for (int i = 0; i < 4; i++)
#pragma unroll
        for (int j = 0; j < 4; j++) acc[i][j] = 0.f;

    int x0 = bx * 64, y0 = by * 64;
    const float* zb  = z  + (size_t)b * D_ * TY_;
    const float* Sb  = S  + (size_t)b * D_ * TX_;
    const float* MSb = MS + (size_t)b * D_ * TX_;

    for (int k0 = 0; k0 < D_; k0 += 16) {
#pragma unroll
        for (int e = tid; e < 1024; e += 256) {
            int kk = e >> 6, ee = e & 63;
            Zt[kk][ee]  = zb[(size_t)(k0 + kk) * TY_ + y0 + ee];
            St[kk][ee]  = Sb[(size_t)(k0 + kk) * TX_ + x0 + ee];
            MSt[kk][ee] = MSb[(size_t)(k0 + kk) * TX_ + x0 + ee];
        }
        __syncthreads();
#pragma unroll
        for (int kk = 0; kk < 16; kk++) {
            float4 zz = *(const float4*)&Zt[kk][ty_ * 4];
            float4 ss = *(const float4*)&St[kk][tx_ * 4];
            float4 mm = *(const float4*)&MSt[kk][tx_ * 4];
            float zA[4] = {zz.x, zz.y, zz.z, zz.w};
            float sA[4] = {ss.x, ss.y, ss.z, ss.w};
            float mA[4] = {mm.x, mm.y, mm.z, mm.w};
#pragma unroll
            for (int i = 0; i < 4; i++) {
                float u = -0.5f * zA[i] * zA[i];
#pragma unroll
                for (int j = 0; j < 4; j++) {
                    acc[i][j] += u * sA[j] + zA[i] * mA[j];
                }
            }
        }
        __syncthreads();
    }

    const float* cb = Cc + b * TX_ + x0 + tx_ * 4;
    float4 cc = *(const float4*)cb;
    float cA[4] = {cc.x, cc.y, cc.z, cc.w};
#pragma unroll
    for (int i = 0; i < 4; i++) {
        int y = y0 + ty_ * 4 + i;
        float4 o;
        o.x = acc[i][0] + cA[0];
        o.y = acc[i][1] + cA[1];
        o.z = acc[i][2] + cA[2];
        o.w = acc[i][3] + cA[3];
        *(float4*)&NC[((size_t)b * TY_ + y) * TX_ + x0 + tx_ * 4] = o;
    }
}

// ============ Kernel C: MAS forward DP, LDS-staged async pipeline ============
// One wave per sample. 2-chunk LDS double buffer (16 rows x 2KB each),
// filled by global_load_lds (width 16) issued 2 chunks (32 rows) ahead.
// LDS->reg via depth-2 float4 ring. Rows 1..2047 real; row 2048 is a dummy
// (clamped load, dirs store lands in unused row 2047 slot).
__global__ __launch_bounds__(64) void mas_forward(const float* __restrict__ NC,
                                                  unsigned char* __restrict__ dirs) {
    int b = blockIdx.x;
    int lane = threadIdx.x;
    const float* ncb = NC + (size_t)b * TY_ * TX_;

    __shared__ __align__(16) float lds[2][16][512];   // 64 KB

    // issue one 2KB row (= 2x global_load_lds dwordx4) into LDS
    auto cp_row = [&](int y, int buf, int slot) {
        if (y > 2047) y = 2047;                        // clamp (dummy row / OOB guard)
        const float* g = ncb + (size_t)y * TX_ + lane * 4;
        float* l = &lds[buf][slot][0];
        __builtin_amdgcn_global_load_lds((glob_f*)g,       (lds_f*)l,         16, 0, 0);
        __builtin_amdgcn_global_load_lds((glob_f*)(g+256), (lds_f*)(l + 256), 16, 0, 0);
    };

    // prefill chunk 0 (rows 1..16) and chunk 1 (rows 17..32)
#pragma unroll
    for (int r = 0; r < 16; r++) cp_row(1 + r, 0, r);
#pragma unroll
    for (int r = 0; r < 16; r++) cp_row(17 + r, 1, r);

    float v[8];
#pragma unroll
    for (int j = 0; j < 8; j++) v[j] = NEGV;
    float nc00 = ncb[0];
    if (lane == 0) v[0] = nc00;

    unsigned char* db = dirs + (size_t)b * 2048 * 64 + lane;

    for (int k = 0; k < 128; k++) {          // chunk k = rows 1+16k .. 16+16k
        int cur = k & 1;
        int y0 = 1 + 16 * k;

        // drain chunk k's 32 loads (chunk k+1's 32 may remain in flight)
        if (k < 126) {
            asm volatile("s_waitcnt vmcnt(32)" ::: "memory");
        } else {
            asm volatile("s_waitcnt vmcnt(0)" ::: "memory");
        }

        // depth-2 register ring over the 16 rows of this chunk
        float4 ra[2], rb[2];
        ra[0] = *(const float4*)&lds[cur][0][lane * 8];
        rb[0] = *(const float4*)&lds[cur][0][lane * 8 + 4];
        ra[1] = *(const float4*)&lds[cur][1][lane * 8];
        rb[1] = *(const float4*)&lds[cur][1][lane * 8 + 4];

#pragma unroll
        for (int r = 0; r < 16; r++) {
            float4 a = ra[r & 1], c = rb[r & 1];
            if (r + 2 < 16) {
                ra[r & 1] = *(const float4*)&lds[cur][r + 2][lane * 8];
                rb[r & 1] = *(const float4*)&lds[cur][r + 2][lane * 8 + 4];
            }
            int y = y0 + r;
            float ncv[8] = {a.x, a.y, a.z, a.w, c.x, c.y, c.z, c.w};
            float bound = __shfl_up(v[7], 1);
            bound = (lane == 0) ? NEGV : bound;
            unsigned bits = 0;
            float carry = bound;
#pragma unroll
            for (int j = 0; j < 8; j++) {
                float vp = v[j];
                float vd = carry;
                carry = vp;
                bits |= ((vd > vp) ? 1u : 0u) << j;
                v[j] = ncv[j] + fmaxf(vp, vd);
            }
            if (y < 511) {                   // mask x > y (only while y < TX_-1)
                int xb = lane * 8;
#pragma unroll
                for (int j = 0; j < 8; j++)
                    if (xb + j > y) v[j] = NEGV;
            }
            db[(size_t)(y - 1) * 64] = (unsigned char)bits;
        }

        // refill this buffer with chunk k+2 (ds_reads above already consumed)
        if (k + 2 < 128) {
            asm volatile("s_waitcnt lgkmcnt(0)" ::: "memory");
#pragma unroll
            for (int r = 0; r < 16; r++) cp_row(1 + 16 * (k + 2) + r, cur, r);
        }
    }
}

// ============ Kernel D: backtrack (one wave per sample, shfl-windowed) ============
__global__ __launch_bounds__(64) void mas_backtrack(const unsigned* __restrict__ dirs,
                                                    int* __restrict__ path) {
    int b = blockIdx.x;
    int lane = threadIdx.x;
    const unsigned* db = dirs + (size_t)b * 2048 * 16;   // 16 dwords per row
    int idx = TX_ - 1;                                   // path[2047]

    for (int y_hi = 2047; y_hi >= 1; y_hi -= 64) {
        int wb = (idx >> 5) - 2;
        if (wb < 0) wb = 0;
        int base = wb << 5;
        int y = y_hi - lane;
        unsigned w0 = 0, w1 = 0, w2 = 0;
        if (y >= 1) {
            const unsigned* r = db + (size_t)(y - 1) * 16 + wb;
            w0 = r[0]; w1 = r[1]; w2 = r[2];
        }
        int steps = (y_hi < 64) ? y_hi : 64;
        int my_path = 0;
#pragma unroll 8
        for (int t = 0; t < steps; t++) {
            if (lane == t) my_path = idx;
            unsigned u0 = (unsigned)__shfl((int)w0, t);
            unsigned u1 = (unsigned)__shfl((int)w1, t);
            unsigned u2 = (unsigned)__shfl((int)w2, t);
            int off = idx - base;
            unsigned w = (off < 32) ? u0 : ((off < 64) ? u1 : u2);
            idx -= (int)((w >> (off & 31)) & 1u);
        }
        if (lane < steps) path[b * TY_ + (y_hi - lane)] = my_path;
    }
    if (lane == 0) path[b * TY_ + 0] = idx;
}

// ============ Kernel E: durations + l_length ============
__global__ __launch_bounds__(512) void durations_ll(const int* __restrict__ path,
                                                    const float* __restrict__ logw,
                                                    float* __restrict__ out_l) {
    int b = blockIdx.x;
    int tid = threadIdx.x;
    __shared__ int wcnt[TX_];
    __shared__ float partial[8];
    wcnt[tid] = 0;
    __syncthreads();
    for (int y = tid; y < TY_; y += 512)
        atomicAdd(&wcnt[path[b * TY_ + y]], 1);
    __syncthreads();
    float t = logw[b * TX_ + tid] - logf((float)wcnt[tid] + 1e-6f);
    float sq = t * t;
#pragma unroll
    for (int off = 32; off > 0; off >>= 1) sq += __shfl_down(sq, off);
    if ((tid & 63) == 0) partial[tid >> 6] = sq;
    __syncthreads();
    if (tid == 0) {
        float s = 0.f;
#pragma unroll
        for (int i = 0; i < 8; i++) s += partial[i];
        out_l[b] = s;
    }
}

// ============ Kernel F: gather out_main ============
__global__ __launch_bounds__(256) void gather_main(const int* __restrict__ path,
                                                   const float* __restrict__ xm,
                                                   const float* __restrict__ xl,
                                                   float* __restrict__ out) {
    int c = blockIdx.x;      // 0..383
    int b = blockIdx.y;      // 0..15
    int tid = threadIdx.x;
    const float* src = (c < D_) ? (xm + ((size_t)b * D_ + c) * TX_)
                                : (xl + ((size_t)b * D_ + (c - D_)) * TX_);
    const int* pb = path + b * TY_;
    float* ob = out + ((size_t)b * 2 * D_ + c) * TY_;
#pragma unroll
    for (int k = 0; k < 8; k++) {
        int y = tid + k * 256;
        ob[y] = src[pb[y]];
    }
}

// ============ Kernel G: write one-hot attn ============
__global__ __launch_bounds__(128) void write_attn(const int* __restrict__ path,
                                                  float* __restrict__ attn) {
    int blk = blockIdx.x;            // b*2048 + y
    int b = blk >> 11;
    int y = blk & 2047;
    int tid = threadIdx.x;           // covers x in [4*tid, 4*tid+4)
    int p = path[b * TY_ + y];
    float4 val = make_float4(0.f, 0.f, 0.f, 0.f);
    if ((p >> 2) == tid) {
        int r = p & 3;
        if (r == 0) val.x = 1.f;
        else if (r == 1) val.y = 1.f;
        else if (r == 2) val.z = 1.f;
        else val.w = 1.f;
    }
    ((float4*)attn)[((size_t)blk) * 128 + tid] = val;
}

extern "C" void kernel_launch(void* const* d_in, const int* in_sizes, int n_in,
                              void* d_out, int out_size, void* d_ws, size_t ws_size,
                              hipStream_t stream) {
    const float* x_mean = (const float*)d_in[0];
    const float* x_logs = (const float*)d_in[1];
    const float* z      = (const float*)d_in[2];
    const float* logw   = (const float*)d_in[3];
    float* out = (float*)d_out;

    char* ws = (char*)d_ws;
    float* S            = (float*)(ws + 0);
    float* MS           = (float*)(ws + 6291456);
    float* Cc           = (float*)(ws + 12582912);
    float* NC           = (float*)(ws + 12615680);
    unsigned char* dirs = (unsigned char*)(ws + 79724544);
    int* path           = (int*)(ws + 81821696);

    float* out_main = out;                 // [B,384,TY]
    float* out_l    = out + 12582912;      // [B]
    float* out_attn = out + 12582928;      // [B,TY,TX]

    precomp<<<dim3(B_), dim3(512), 0, stream>>>(x_mean, x_logs, S, MS, Cc);
    gemm_nc<<<dim3(8, 32, 16), dim3(256), 0, stream>>>(z, S, MS, Cc, NC);
    mas_forward<<<dim3(B_), dim3(64), 0, stream>>>(NC, dirs);
    mas_backtrack<<<dim3(B_), dim3(64), 0, stream>>>((const unsigned*)dirs, path);
    durations_ll<<<dim3(B_), dim3(512), 0, stream>>>(path, logw, out_l);
    gather_main<<<dim3(384, 16), dim3(256), 0, stream>>>(path, x_mean, x_logs, out_main);
    write_attn<<<dim3(B_ * TY_), dim3(128), 0, stream>>>(path, out_attn);
}

// Round 3
// 983.057 us; speedup vs baseline: 1.0469x; 1.0323x over previous
//
#include <hip/hip_runtime.h>
#include <hip/hip_bf16.h>
#include <math.h>

#define B_   16
#define D_   192
#define TX_  512
#define TY_  2048
#define NEGV (-1e9f)

// -------- workspace layout (bytes) --------
// S    : B*D*TX f32   @ 0          (6,291,456)
// MS   : B*D*TX f32   @ 6291456    (6,291,456)
// (gap: 32,768 — old Cc slot, unused)
// NC   : B*TY*TX f32  @ 12615680   (67,108,864)
// dirs : B*2048*64 u8 @ 79724544   (2,097,152)   [aliased: Cpart B*6*TX f32 in
//         first 196,608 B — consumed by gemm_nc BEFORE mas_forward writes dirs]
// path : B*TY  i32    @ 81821696   (131,072)

// -------- output layout (f32 elements) --------
// out_main [B,384,TY] @ 0, l_length [B] @ 12582912, attn [B,TY,TX] @ 12582928

typedef __attribute__((address_space(1))) const float glob_f;
typedef __attribute__((address_space(3))) float       lds_f;

// ============ Kernel A: precompute S, MS, partial C (deterministic) ============
// grid (B, 6); block p handles d in [32p, 32p+32).
__global__ __launch_bounds__(512) void precomp(const float* __restrict__ xm,
                                               const float* __restrict__ xl,
                                               float* __restrict__ S,
                                               float* __restrict__ MS,
                                               float* __restrict__ Cpart) {
    int b = blockIdx.x;
    int p = blockIdx.y;
    int x = threadIdx.x;
    size_t base = ((size_t)b * D_ + p * 32) * TX_;
    const float* mb = xm + base;
    const float* lb = xl + base;
    float* Sb  = S  + base;
    float* MSb = MS + base;
    float c = 0.f;
    for (int d = 0; d < 32; d++) {
        float lg = lb[d * TX_ + x];
        float mn = mb[d * TX_ + x];
        float s  = expf(-2.f * lg);
        float ms = mn * s;
        Sb[d * TX_ + x]  = s;
        MSb[d * TX_ + x] = ms;
        c += -0.9189385332046727f - lg - 0.5f * mn * mn * s;   // nc1 + nc4 terms
    }
    Cpart[(b * 6 + p) * TX_ + x] = c;
}

// ============ Kernel B: NC = A(z)*B(s,ms) + c, f32 128x128 tile, 8x8 micro ============
// grid (4, 16, 16), 256 threads (16x16). Column/row splits of 4 floats at
// offsets {t*4, t*4+64}: lane bank stride 4 -> 2-way LDS aliasing (free, m136).
__global__ __launch_bounds__(256) void gemm_nc(const float* __restrict__ z,
                                               const float* __restrict__ S,
                                               const float* __restrict__ MS,
                                               const float* __restrict__ Cpart,
                                               float* __restrict__ NC) {
    int bx = blockIdx.x;            // 4  -> x tiles of 128
    int by = blockIdx.y;            // 16 -> y tiles of 128
    int b  = blockIdx.z;            // 16
    int tid = threadIdx.x;
    int tx = tid & 15, ty = tid >> 4;
    __shared__ __align__(16) float Zt[16 * 128];
    __shared__ __align__(16) float St[16 * 128];
    __shared__ __align__(16) float MSt[16 * 128];

    float acc[8][8];
#pragma unroll
    for (int i = 0; i < 8; i++)
#pragma unroll
        for (int j = 0; j < 8; j++) acc[i][j] = 0.f;

    int x0 = bx * 128, y0 = by * 128;
    const float* zb  = z  + (size_t)b * D_ * TY_;
    const float* Sb  = S  + (size_t)b * D_ * TX_;
    const float* MSb = MS + (size_t)b * D_ * TX_;

    for (int k0 = 0; k0 < D_; k0 += 16) {
        // stage 3 x (16 rows x 128 cols) via async global->LDS, 16B per lane
#pragma unroll
        for (int j = 0; j < 2; j++) {
            int f = tid + j * 256;          // 0..511 float4 slots
            int kk = f >> 5, c = (f & 31) * 4;
            __builtin_amdgcn_global_load_lds((glob_f*)(zb  + (size_t)(k0 + kk) * TY_ + y0 + c),
                                             (lds_f*)(Zt  + f * 4), 16, 0, 0);
            __builtin_amdgcn_global_load_lds((glob_f*)(Sb  + (size_t)(k0 + kk) * TX_ + x0 + c),
                                             (lds_f*)(St  + f * 4), 16, 0, 0);
            __builtin_amdgcn_global_load_lds((glob_f*)(MSb + (size_t)(k0 + kk) * TX_ + x0 + c),
                                             (lds_f*)(MSt + f * 4), 16, 0, 0);
        }
        __syncthreads();

#pragma unroll
        for (int kk = 0; kk < 16; kk++) {
            float4 z0 = *(const float4*)&Zt[kk * 128 + ty * 4];
            float4 z1 = *(const float4*)&Zt[kk * 128 + 64 + ty * 4];
            float4 s0 = *(const float4*)&St[kk * 128 + tx * 4];
            float4 s1 = *(const float4*)&St[kk * 128 + 64 + tx * 4];
            float4 m0 = *(const float4*)&MSt[kk * 128 + tx * 4];
            float4 m1 = *(const float4*)&MSt[kk * 128 + 64 + tx * 4];
            float zz[8] = {z0.x, z0.y, z0.z, z0.w, z1.x, z1.y, z1.z, z1.w};
            float ss[8] = {s0.x, s0.y, s0.z, s0.w, s1.x, s1.y, s1.z, s1.w};
            float mm[8] = {m0.x, m0.y, m0.z, m0.w, m1.x, m1.y, m1.z, m1.w};
            float uu[8];
#pragma unroll
            for (int i = 0; i < 8; i++) uu[i] = -0.5f * zz[i] * zz[i];
#pragma unroll
            for (int i = 0; i < 8; i++)
#pragma unroll
                for (int j = 0; j < 8; j++)
                    acc[i][j] += uu[i] * ss[j] + zz[i] * mm[j];
        }
        __syncthreads();
    }

    // column constants: sum 6 deterministic partials
    float cv[8] = {0, 0, 0, 0, 0, 0, 0, 0};
#pragma unroll
    for (int p = 0; p < 6; p++) {
        float4 c0 = *(const float4*)&Cpart[(b * 6 + p) * TX_ + x0 + tx * 4];
        float4 c1 = *(const float4*)&Cpart[(b * 6 + p) * TX_ + x0 + 64 + tx * 4];
        cv[0] += c0.x; cv[1] += c0.y; cv[2] += c0.z; cv[3] += c0.w;
        cv[4] += c1.x; cv[5] += c1.y; cv[6] += c1.z; cv[7] += c1.w;
    }

#pragma unroll
    for (int i = 0; i < 8; i++) {
        int y = y0 + ty * 4 + (i & 3) + 64 * (i >> 2);
        float4 o0, o1;
        o0.x = acc[i][0] + cv[0]; o0.y = acc[i][1] + cv[1];
        o0.z = acc[i][2] + cv[2]; o0.w = acc[i][3] + cv[3];
        o1.x = acc[i][4] + cv[4]; o1.y = acc[i][5] + cv[5];
        o1.z = acc[i][6] + cv[6]; o1.w = acc[i][7] + cv[7];
        *(float4*)&NC[((size_t)b * TY_ + y) * TX_ + x0 + tx * 4]      = o0;
        *(float4*)&NC[((size_t)b * TY_ + y) * TX_ + x0 + 64 + tx * 4] = o1;
    }
}

// ============ Kernel C: MAS forward DP — pure VGPR ring, depth 16 ============
// One wave per sample. NO LDS, NO conditionals in steady state: 127 blocks
// of 16 unconditional rows; loads issued 16 rows (~1400 cy of work) ahead.
// Tail loads (row 2048) read the dirs region (harmless, never consumed).
__global__ __launch_bounds__(64) void mas_forward(const float* __restrict__ NC,
                                                  unsigned char* __restrict__ dirs) {
    int b = blockIdx.x;
    int lane = threadIdx.x;
    const float* ncb = NC + (size_t)b * TY_ * TX_;
    const float4* base = (const float4*)ncb + lane * 2;   // row y -> + y*128

    float4 A[16], C[16];
#pragma unroll
    for (int s = 0; s < 16; s++) {
        A[s] = base[(size_t)(1 + s) * 128];
        C[s] = base[(size_t)(1 + s) * 128 + 1];
    }

    float v[8];
#pragma unroll
    for (int j = 0; j < 8; j++) v[j] = NEGV;
    if (lane == 0) v[0] = ncb[0];

    unsigned char* db = dirs + (size_t)b * 2048 * 64 + lane;

    auto row_step = [&](float4 a, float4 c, int y, bool mask) {
        float ncv[8] = {a.x, a.y, a.z, a.w, c.x, c.y, c.z, c.w};
        float bound = __shfl_up(v[7], 1);
        if (lane == 0) bound = NEGV;
        unsigned bits = 0;
        float vd = bound;
#pragma unroll
        for (int j = 0; j < 8; j++) {
            float vp = v[j];
            bits |= (vd > vp) ? (1u << j) : 0u;
            v[j] = ncv[j] + fmaxf(vp, vd);
            vd = vp;
        }
        if (mask && y < 511) {
            int xb = lane * 8;
#pragma unroll
            for (int j = 0; j < 8; j++)
                if (xb + j > y) v[j] = NEGV;
        }
        db[(size_t)(y - 1) * 64] = (unsigned char)bits;
    };

    int y = 1;
    // masked phase: blocks 0..31 (rows 1..512)
    for (int k = 0; k < 32; k++) {
#pragma unroll
        for (int s = 0; s < 16; s++) {
            float4 a = A[s], c = C[s];
            A[s] = base[(size_t)(y + 16) * 128];
            C[s] = base[(size_t)(y + 16) * 128 + 1];
            row_step(a, c, y, true);
            y++;
        }
    }
    // unmasked phase: blocks 32..126 (rows 513..2032)
    for (int k = 32; k < 127; k++) {
#pragma unroll
        for (int s = 0; s < 16; s++) {
            float4 a = A[s], c = C[s];
            A[s] = base[(size_t)(y + 16) * 128];
            C[s] = base[(size_t)(y + 16) * 128 + 1];
            row_step(a, c, y, false);
            y++;
        }
    }
    // epilogue: rows 2033..2047 from ring slots 0..14 (no more loads)
#pragma unroll
    for (int s = 0; s < 15; s++) {
        row_step(A[s], C[s], y, false);
        y++;
    }
}

// ============ Kernel D: backtrack (one wave per sample, shfl-windowed) ============
__global__ __launch_bounds__(64) void mas_backtrack(const unsigned* __restrict__ dirs,
                                                    int* __restrict__ path) {
    int b = blockIdx.x;
    int lane = threadIdx.x;
    const unsigned* db = dirs + (size_t)b * 2048 * 16;   // 16 dwords per row
    int idx = TX_ - 1;                                   // path[2047]

    for (int y_hi = 2047; y_hi >= 1; y_hi -= 64) {
        int wb = (idx >> 5) - 2;
        if (wb < 0) wb = 0;
        int base = wb << 5;
        int y = y_hi - lane;
        unsigned w0 = 0, w1 = 0, w2 = 0;
        if (y >= 1) {
            const unsigned* r = db + (size_t)(y - 1) * 16 + wb;
            w0 = r[0]; w1 = r[1]; w2 = r[2];
        }
        int steps = (y_hi < 64) ? y_hi : 64;
        int my_path = 0;
#pragma unroll 8
        for (int t = 0; t < steps; t++) {
            if (lane == t) my_path = idx;
            unsigned u0 = (unsigned)__shfl((int)w0, t);
            unsigned u1 = (unsigned)__shfl((int)w1, t);
            unsigned u2 = (unsigned)__shfl((int)w2, t);
            int off = idx - base;
            unsigned w = (off < 32) ? u0 : ((off < 64) ? u1 : u2);
            idx -= (int)((w >> (off & 31)) & 1u);
        }
        if (lane < steps) path[b * TY_ + (y_hi - lane)] = my_path;
    }
    if (lane == 0) path[b * TY_ + 0] = idx;
}

// ============ Kernel E: durations + l_length ============
__global__ __launch_bounds__(512) void durations_ll(const int* __restrict__ path,
                                                    const float* __restrict__ logw,
                                                    float* __restrict__ out_l) {
    int b = blockIdx.x;
    int tid = threadIdx.x;
    __shared__ int wcnt[TX_];
    __shared__ float partial[8];
    wcnt[tid] = 0;
    __syncthreads();
    for (int y = tid; y < TY_; y += 512)
        atomicAdd(&wcnt[path[b * TY_ + y]], 1);
    __syncthreads();
    float t = logw[b * TX_ + tid] - logf((float)wcnt[tid] + 1e-6f);
    float sq = t * t;
#pragma unroll
    for (int off = 32; off > 0; off >>= 1) sq += __shfl_down(sq, off);
    if ((tid & 63) == 0) partial[tid >> 6] = sq;
    __syncthreads();
    if (tid == 0) {
        float s = 0.f;
#pragma unroll
        for (int i = 0; i < 8; i++) s += partial[i];
        out_l[b] = s;
    }
}

// ============ Kernel F: gather out_main ============
__global__ __launch_bounds__(256) void gather_main(const int* __restrict__ path,
                                                   const float* __restrict__ xm,
                                                   const float* __restrict__ xl,
                                                   float* __restrict__ out) {
    int c = blockIdx.x;      // 0..383
    int b = blockIdx.y;      // 0..15
    int tid = threadIdx.x;
    const float* src = (c < D_) ? (xm + ((size_t)b * D_ + c) * TX_)
                                : (xl + ((size_t)b * D_ + (c - D_)) * TX_);
    const int* pb = path + b * TY_;
    float* ob = out + ((size_t)b * 2 * D_ + c) * TY_;
#pragma unroll
    for (int k = 0; k < 8; k++) {
        int y = tid + k * 256;
        ob[y] = src[pb[y]];
    }
}

// ============ Kernel G: write one-hot attn ============
__global__ __launch_bounds__(128) void write_attn(const int* __restrict__ path,
                                                  float* __restrict__ attn) {
    int blk = blockIdx.x;            // b*2048 + y
    int b = blk >> 11;
    int y = blk & 2047;
    int tid = threadIdx.x;           // covers x in [4*tid, 4*tid+4)
    int p = path[b * TY_ + y];
    float4 val = make_float4(0.f, 0.f, 0.f, 0.f);
    if ((p >> 2) == tid) {
        int r = p & 3;
        if (r == 0) val.x = 1.f;
        else if (r == 1) val.y = 1.f;
        else if (r == 2) val.z = 1.f;
        else val.w = 1.f;
    }
    ((float4*)attn)[((size_t)blk) * 128 + tid] = val;
}

extern "C" void kernel_launch(void* const* d_in, const int* in_sizes, int n_in,
                              void* d_out, int out_size, void* d_ws, size_t ws_size,
                              hipStream_t stream) {
    const float* x_mean = (const float*)d_in[0];
    const float* x_logs = (const float*)d_in[1];
    const float* z      = (const float*)d_in[2];
    const float* logw   = (const float*)d_in[3];
    float* out = (float*)d_out;

    char* ws = (char*)d_ws;
    float* S            = (float*)(ws + 0);
    float* MS           = (float*)(ws + 6291456);
    float* NC           = (float*)(ws + 12615680);
    unsigned char* dirs = (unsigned char*)(ws + 79724544);
    float* Cpart        = (float*)(ws + 79724544);   // aliases dirs; dead before mas_forward
    int* path           = (int*)(ws + 81821696);

    float* out_main = out;                 // [B,384,TY]
    float* out_l    = out + 12582912;      // [B]
    float* out_attn = out + 12582928;      // [B,TY,TX]

    precomp<<<dim3(B_, 6), dim3(512), 0, stream>>>(x_mean, x_logs, S, MS, Cpart);
    gemm_nc<<<dim3(4, 16, 16), dim3(256), 0, stream>>>(z, S, MS, Cpart, NC);
    mas_forward<<<dim3(B_), dim3(64), 0, stream>>>(NC, dirs);
    mas_backtrack<<<dim3(B_), dim3(64), 0, stream>>>((const unsigned*)dirs, path);
    durations_ll<<<dim3(B_), dim3(512), 0, stream>>>(path, logw, out_l);
    gather_main<<<dim3(384, 16), dim3(256), 0, stream>>>(path, x_mean, x_logs, out_main);
    write_attn<<<dim3(B_ * TY_), dim3(128), 0, stream>>>(path, out_attn);
}

// Round 4
// 786.441 us; speedup vs baseline: 1.3087x; 1.2500x over previous
//
#include <hip/hip_runtime.h>
#include <hip/hip_bf16.h>
#include <math.h>

#define B_   16
#define D_   192
#define TX_  512
#define TY_  2048
#define NEGV (-1e9f)

// -------- workspace layout (bytes) --------
// S    : B*D*TX f32   @ 0          (6,291,456)
// MS   : B*D*TX f32   @ 6291456    (6,291,456)
// NC   : B*TY*TX f32  @ 12615680   (67,108,864)
// dirs : B*2048*64 u8 @ 79724544   (2,097,152)   [aliased: Cpart B*6*TX f32 in
//         first 196,608 B — consumed by gemm_nc BEFORE mas_forward writes dirs]
// path : B*TY  i32    @ 81821696   (131,072)

// -------- output layout (f32 elements) --------
// out_main [B,384,TY] @ 0, l_length [B] @ 12582912, attn [B,TY,TX] @ 12582928

typedef __attribute__((address_space(1))) const float glob_f;
typedef __attribute__((address_space(3))) float       lds_f;

// ============ Kernel A: precompute S, MS, partial C (deterministic) ============
__global__ __launch_bounds__(512) void precomp(const float* __restrict__ xm,
                                               const float* __restrict__ xl,
                                               float* __restrict__ S,
                                               float* __restrict__ MS,
                                               float* __restrict__ Cpart) {
    int b = blockIdx.x;
    int p = blockIdx.y;
    int x = threadIdx.x;
    size_t base = ((size_t)b * D_ + p * 32) * TX_;
    const float* mb = xm + base;
    const float* lb = xl + base;
    float* Sb  = S  + base;
    float* MSb = MS + base;
    float c = 0.f;
    for (int d = 0; d < 32; d++) {
        float lg = lb[d * TX_ + x];
        float mn = mb[d * TX_ + x];
        float s  = expf(-2.f * lg);
        float ms = mn * s;
        Sb[d * TX_ + x]  = s;
        MSb[d * TX_ + x] = ms;
        c += -0.9189385332046727f - lg - 0.5f * mn * mn * s;   // nc1 + nc4 terms
    }
    Cpart[(b * 6 + p) * TX_ + x] = c;
}

// ============ Kernel B: NC = A(z)*B(s,ms) + c, f32 128x128 tile, 8x8 micro ============
// unroll 2 on kk: keeps live set ~160 VGPR (R3's full unroll spilled at 256).
__global__ __launch_bounds__(256) void gemm_nc(const float* __restrict__ z,
                                               const float* __restrict__ S,
                                               const float* __restrict__ MS,
                                               const float* __restrict__ Cpart,
                                               float* __restrict__ NC) {
    int bx = blockIdx.x;            // 4  -> x tiles of 128
    int by = blockIdx.y;            // 16 -> y tiles of 128
    int b  = blockIdx.z;            // 16
    int tid = threadIdx.x;
    int tx = tid & 15, ty = tid >> 4;
    __shared__ __align__(16) float Zt[16 * 128];
    __shared__ __align__(16) float St[16 * 128];
    __shared__ __align__(16) float MSt[16 * 128];

    float acc[8][8];
#pragma unroll
    for (int i = 0; i < 8; i++)
#pragma unroll
        for (int j = 0; j < 8; j++) acc[i][j] = 0.f;

    int x0 = bx * 128, y0 = by * 128;
    const float* zb  = z  + (size_t)b * D_ * TY_;
    const float* Sb  = S  + (size_t)b * D_ * TX_;
    const float* MSb = MS + (size_t)b * D_ * TX_;

    for (int k0 = 0; k0 < D_; k0 += 16) {
        // stage 3 x (16 rows x 128 cols) via async global->LDS, 16B per lane
#pragma unroll
        for (int j = 0; j < 2; j++) {
            int f = tid + j * 256;          // 0..511 float4 slots
            int kk = f >> 5, c = (f & 31) * 4;
            __builtin_amdgcn_global_load_lds((glob_f*)(zb  + (size_t)(k0 + kk) * TY_ + y0 + c),
                                             (lds_f*)(Zt  + f * 4), 16, 0, 0);
            __builtin_amdgcn_global_load_lds((glob_f*)(Sb  + (size_t)(k0 + kk) * TX_ + x0 + c),
                                             (lds_f*)(St  + f * 4), 16, 0, 0);
            __builtin_amdgcn_global_load_lds((glob_f*)(MSb + (size_t)(k0 + kk) * TX_ + x0 + c),
                                             (lds_f*)(MSt + f * 4), 16, 0, 0);
        }
        __syncthreads();

#pragma unroll 2
        for (int kk = 0; kk < 16; kk++) {
            float4 z0 = *(const float4*)&Zt[kk * 128 + ty * 4];
            float4 z1 = *(const float4*)&Zt[kk * 128 + 64 + ty * 4];
            float4 s0 = *(const float4*)&St[kk * 128 + tx * 4];
            float4 s1 = *(const float4*)&St[kk * 128 + 64 + tx * 4];
            float4 m0 = *(const float4*)&MSt[kk * 128 + tx * 4];
            float4 m1 = *(const float4*)&MSt[kk * 128 + 64 + tx * 4];
            float4 u0, u1;
            u0.x = -0.5f * z0.x * z0.x; u0.y = -0.5f * z0.y * z0.y;
            u0.z = -0.5f * z0.z * z0.z; u0.w = -0.5f * z0.w * z0.w;
            u1.x = -0.5f * z1.x * z1.x; u1.y = -0.5f * z1.y * z1.y;
            u1.z = -0.5f * z1.z * z1.z; u1.w = -0.5f * z1.w * z1.w;
            float zz[8] = {z0.x, z0.y, z0.z, z0.w, z1.x, z1.y, z1.z, z1.w};
            float uu[8] = {u0.x, u0.y, u0.z, u0.w, u1.x, u1.y, u1.z, u1.w};
            float ss[8] = {s0.x, s0.y, s0.z, s0.w, s1.x, s1.y, s1.z, s1.w};
            float mm[8] = {m0.x, m0.y, m0.z, m0.w, m1.x, m1.y, m1.z, m1.w};
#pragma unroll
            for (int i = 0; i < 8; i++)
#pragma unroll
                for (int j = 0; j < 8; j++)
                    acc[i][j] += uu[i] * ss[j] + zz[i] * mm[j];
        }
        __syncthreads();
    }

    // column constants: sum 6 deterministic partials
    float cv[8] = {0, 0, 0, 0, 0, 0, 0, 0};
#pragma unroll
    for (int p = 0; p < 6; p++) {
        float4 c0 = *(const float4*)&Cpart[(b * 6 + p) * TX_ + x0 + tx * 4];
        float4 c1 = *(const float4*)&Cpart[(b * 6 + p) * TX_ + x0 + 64 + tx * 4];
        cv[0] += c0.x; cv[1] += c0.y; cv[2] += c0.z; cv[3] += c0.w;
        cv[4] += c1.x; cv[5] += c1.y; cv[6] += c1.z; cv[7] += c1.w;
    }

#pragma unroll
    for (int i = 0; i < 8; i++) {
        int y = y0 + ty * 4 + (i & 3) + 64 * (i >> 2);
        float4 o0, o1;
        o0.x = acc[i][0] + cv[0]; o0.y = acc[i][1] + cv[1];
        o0.z = acc[i][2] + cv[2]; o0.w = acc[i][3] + cv[3];
        o1.x = acc[i][4] + cv[4]; o1.y = acc[i][5] + cv[5];
        o1.z = acc[i][6] + cv[6]; o1.w = acc[i][7] + cv[7];
        *(float4*)&NC[((size_t)b * TY_ + y) * TX_ + x0 + tx * 4]      = o0;
        *(float4*)&NC[((size_t)b * TY_ + y) * TX_ + x0 + 64 + tx * 4] = o1;
    }
}

// ============ Kernel C: MAS forward DP — pure VGPR ring, depth 16 ============
__global__ __launch_bounds__(64) void mas_forward(const float* __restrict__ NC,
                                                  unsigned char* __restrict__ dirs) {
    int b = blockIdx.x;
    int lane = threadIdx.x;
    const float* ncb = NC + (size_t)b * TY_ * TX_;
    const float4* base = (const float4*)ncb + lane * 2;   // row y -> + y*128

    float4 A[16], C[16];
#pragma unroll
    for (int s = 0; s < 16; s++) {
        A[s] = base[(size_t)(1 + s) * 128];
        C[s] = base[(size_t)(1 + s) * 128 + 1];
    }

    float v[8];
#pragma unroll
    for (int j = 0; j < 8; j++) v[j] = NEGV;
    if (lane == 0) v[0] = ncb[0];

    unsigned char* db = dirs + (size_t)b * 2048 * 64 + lane;

    auto row_step = [&](float4 a, float4 c, int y, bool mask) {
        float ncv[8] = {a.x, a.y, a.z, a.w, c.x, c.y, c.z, c.w};
        float bound = __shfl_up(v[7], 1);
        if (lane == 0) bound = NEGV;
        unsigned bits = 0;
        float vd = bound;
#pragma unroll
        for (int j = 0; j < 8; j++) {
            float vp = v[j];
            bits |= (vd > vp) ? (1u << j) : 0u;
            v[j] = ncv[j] + fmaxf(vp, vd);
            vd = vp;
        }
        if (mask && y < 511) {
            int xb = lane * 8;
#pragma unroll
            for (int j = 0; j < 8; j++)
                if (xb + j > y) v[j] = NEGV;
        }
        db[(size_t)(y - 1) * 64] = (unsigned char)bits;
    };

    int y = 1;
    for (int k = 0; k < 32; k++) {
#pragma unroll
        for (int s = 0; s < 16; s++) {
            float4 a = A[s], c = C[s];
            A[s] = base[(size_t)(y + 16) * 128];
            C[s] = base[(size_t)(y + 16) * 128 + 1];
            row_step(a, c, y, true);
            y++;
        }
    }
    for (int k = 32; k < 127; k++) {
#pragma unroll
        for (int s = 0; s < 16; s++) {
            float4 a = A[s], c = C[s];
            A[s] = base[(size_t)(y + 16) * 128];
            C[s] = base[(size_t)(y + 16) * 128 + 1];
            row_step(a, c, y, false);
            y++;
        }
    }
#pragma unroll
    for (int s = 0; s < 15; s++) {
        row_step(A[s], C[s], y, false);
        y++;
    }
}

// ============ Kernel D: backtrack (one wave per sample, shfl-windowed) ============
__global__ __launch_bounds__(64) void mas_backtrack(const unsigned* __restrict__ dirs,
                                                    int* __restrict__ path) {
    int b = blockIdx.x;
    int lane = threadIdx.x;
    const unsigned* db = dirs + (size_t)b * 2048 * 16;   // 16 dwords per row
    int idx = TX_ - 1;                                   // path[2047]

    for (int y_hi = 2047; y_hi >= 1; y_hi -= 64) {
        int wb = (idx >> 5) - 2;
        if (wb < 0) wb = 0;
        int base = wb << 5;
        int y = y_hi - lane;
        unsigned w0 = 0, w1 = 0, w2 = 0;
        if (y >= 1) {
            const unsigned* r = db + (size_t)(y - 1) * 16 + wb;
            w0 = r[0]; w1 = r[1]; w2 = r[2];
        }
        int steps = (y_hi < 64) ? y_hi : 64;
        int my_path = 0;
#pragma unroll 8
        for (int t = 0; t < steps; t++) {
            if (lane == t) my_path = idx;
            unsigned u0 = (unsigned)__shfl((int)w0, t);
            unsigned u1 = (unsigned)__shfl((int)w1, t);
            unsigned u2 = (unsigned)__shfl((int)w2, t);
            int off = idx - base;
            unsigned w = (off < 32) ? u0 : ((off < 64) ? u1 : u2);
            idx -= (int)((w >> (off & 31)) & 1u);
        }
        if (lane < steps) path[b * TY_ + (y_hi - lane)] = my_path;
    }
    if (lane == 0) path[b * TY_ + 0] = idx;
}

// ============ Kernel E: durations + l_length ============
__global__ __launch_bounds__(512) void durations_ll(const int* __restrict__ path,
                                                    const float* __restrict__ logw,
                                                    float* __restrict__ out_l) {
    int b = blockIdx.x;
    int tid = threadIdx.x;
    __shared__ int wcnt[TX_];
    __shared__ float partial[8];
    wcnt[tid] = 0;
    __syncthreads();
    for (int y = tid; y < TY_; y += 512)
        atomicAdd(&wcnt[path[b * TY_ + y]], 1);
    __syncthreads();
    float t = logw[b * TX_ + tid] - logf((float)wcnt[tid] + 1e-6f);
    float sq = t * t;
#pragma unroll
    for (int off = 32; off > 0; off >>= 1) sq += __shfl_down(sq, off);
    if ((tid & 63) == 0) partial[tid >> 6] = sq;
    __syncthreads();
    if (tid == 0) {
        float s = 0.f;
#pragma unroll
        for (int i = 0; i < 8; i++) s += partial[i];
        out_l[b] = s;
    }
}

// ============ Kernel F: gather out_main ============
__global__ __launch_bounds__(256) void gather_main(const int* __restrict__ path,
                                                   const float* __restrict__ xm,
                                                   const float* __restrict__ xl,
                                                   float* __restrict__ out) {
    int c = blockIdx.x;      // 0..383
    int b = blockIdx.y;      // 0..15
    int tid = threadIdx.x;
    const float* src = (c < D_) ? (xm + ((size_t)b * D_ + c) * TX_)
                                : (xl + ((size_t)b * D_ + (c - D_)) * TX_);
    const int* pb = path + b * TY_;
    float* ob = out + ((size_t)b * 2 * D_ + c) * TY_;
#pragma unroll
    for (int k = 0; k < 8; k++) {
        int y = tid + k * 256;
        ob[y] = src[pb[y]];
    }
}

// ============ Kernel G: write one-hot attn ============
__global__ __launch_bounds__(128) void write_attn(const int* __restrict__ path,
                                                  float* __restrict__ attn) {
    int blk = blockIdx.x;            // b*2048 + y
    int b = blk >> 11;
    int y = blk & 2047;
    int tid = threadIdx.x;           // covers x in [4*tid, 4*tid+4)
    int p = path[b * TY_ + y];
    float4 val = make_float4(0.f, 0.f, 0.f, 0.f);
    if ((p >> 2) == tid) {
        int r = p & 3;
        if (r == 0) val.x = 1.f;
        else if (r == 1) val.y = 1.f;
        else if (r == 2) val.z = 1.f;
        else val.w = 1.f;
    }
    ((float4*)attn)[((size_t)blk) * 128 + tid] = val;
}

extern "C" void kernel_launch(void* const* d_in, const int* in_sizes, int n_in,
                              void* d_out, int out_size, void* d_ws, size_t ws_size,
                              hipStream_t stream) {
    const float* x_mean = (const float*)d_in[0];
    const float* x_logs = (const float*)d_in[1];
    const float* z      = (const float*)d_in[2];
    const float* logw   = (const float*)d_in[3];
    float* out = (float*)d_out;

    char* ws = (char*)d_ws;
    float* S            = (float*)(ws + 0);
    float* MS           = (float*)(ws + 6291456);
    float* NC           = (float*)(ws + 12615680);
    unsigned char* dirs = (unsigned char*)(ws + 79724544);
    float* Cpart        = (float*)(ws + 79724544);   // aliases dirs; dead before mas_forward
    int* path           = (int*)(ws + 81821696);

    float* out_main = out;                 // [B,384,TY]
    float* out_l    = out + 12582912;      // [B]
    float* out_attn = out + 12582928;      // [B,TY,TX]

    precomp<<<dim3(B_, 6), dim3(512), 0, stream>>>(x_mean, x_logs, S, MS, Cpart);
    gemm_nc<<<dim3(4, 16, 16), dim3(256), 0, stream>>>(z, S, MS, Cpart, NC);
    mas_forward<<<dim3(B_), dim3(64), 0, stream>>>(NC, dirs);
    mas_backtrack<<<dim3(B_), dim3(64), 0, stream>>>((const unsigned*)dirs, path);
    durations_ll<<<dim3(B_), dim3(512), 0, stream>>>(path, logw, out_l);
    gather_main<<<dim3(384, 16), dim3(256), 0, stream>>>(path, x_mean, x_logs, out_main);
    write_attn<<<dim3(B_ * TY_), dim3(128), 0, stream>>>(path, out_attn);
}

// Round 5
// 752.319 us; speedup vs baseline: 1.3681x; 1.0454x over previous
//
#include <hip/hip_runtime.h>
#include <hip/hip_bf16.h>
#include <math.h>

#define B_   16
#define D_   192
#define TX_  512
#define TY_  2048
#define NEGV (-1e9f)

// -------- workspace layout (bytes) --------
// S    : B*D*TX f32   @ 0          (6,291,456)
// MS   : B*D*TX f32   @ 6291456    (6,291,456)
// NC   : B*TY*TX f32  @ 12615680   (67,108,864)
// dirs : B*2048*64 u8 @ 79724544   (2,097,152)   [aliased: Cpart B*6*TX f32 in
//         first 196,608 B — consumed by gemm_nc BEFORE mas_forward writes dirs]
// path : B*TY  i32    @ 81821696   (131,072)

// -------- output layout (f32 elements) --------
// out_main [B,384,TY] @ 0, l_length [B] @ 12582912, attn [B,TY,TX] @ 12582928

typedef __attribute__((address_space(1))) const float glob_f;
typedef __attribute__((address_space(3))) float       lds_f;

// ============ Kernel A: precompute S, MS, partial C (deterministic) ============
__global__ __launch_bounds__(512) void precomp(const float* __restrict__ xm,
                                               const float* __restrict__ xl,
                                               float* __restrict__ S,
                                               float* __restrict__ MS,
                                               float* __restrict__ Cpart) {
    int b = blockIdx.x;
    int p = blockIdx.y;
    int x = threadIdx.x;
    size_t base = ((size_t)b * D_ + p * 32) * TX_;
    const float* mb = xm + base;
    const float* lb = xl + base;
    float* Sb  = S  + base;
    float* MSb = MS + base;
    float c = 0.f;
    for (int d = 0; d < 32; d++) {
        float lg = lb[d * TX_ + x];
        float mn = mb[d * TX_ + x];
        float s  = expf(-2.f * lg);
        float ms = mn * s;
        Sb[d * TX_ + x]  = s;
        MSb[d * TX_ + x] = ms;
        c += -0.9189385332046727f - lg - 0.5f * mn * mn * s;   // nc1 + nc4 terms
    }
    Cpart[(b * 6 + p) * TX_ + x] = c;
}

// ============ Kernel B: NC = A(z)*B(s,ms) + c, f32 128x128 tile, 8x8 micro ============
// unroll 2 on kk: keeps live set ~160 VGPR (R3's full unroll spilled at 256).
__global__ __launch_bounds__(256) void gemm_nc(const float* __restrict__ z,
                                               const float* __restrict__ S,
                                               const float* __restrict__ MS,
                                               const float* __restrict__ Cpart,
                                               float* __restrict__ NC) {
    int bx = blockIdx.x;            // 4  -> x tiles of 128
    int by = blockIdx.y;            // 16 -> y tiles of 128
    int b  = blockIdx.z;            // 16
    int tid = threadIdx.x;
    int tx = tid & 15, ty = tid >> 4;
    __shared__ __align__(16) float Zt[16 * 128];
    __shared__ __align__(16) float St[16 * 128];
    __shared__ __align__(16) float MSt[16 * 128];

    float acc[8][8];
#pragma unroll
    for (int i = 0; i < 8; i++)
#pragma unroll
        for (int j = 0; j < 8; j++) acc[i][j] = 0.f;

    int x0 = bx * 128, y0 = by * 128;
    const float* zb  = z  + (size_t)b * D_ * TY_;
    const float* Sb  = S  + (size_t)b * D_ * TX_;
    const float* MSb = MS + (size_t)b * D_ * TX_;

    for (int k0 = 0; k0 < D_; k0 += 16) {
        // stage 3 x (16 rows x 128 cols) via async global->LDS, 16B per lane
#pragma unroll
        for (int j = 0; j < 2; j++) {
            int f = tid + j * 256;          // 0..511 float4 slots
            int kk = f >> 5, c = (f & 31) * 4;
            __builtin_amdgcn_global_load_lds((glob_f*)(zb  + (size_t)(k0 + kk) * TY_ + y0 + c),
                                             (lds_f*)(Zt  + f * 4), 16, 0, 0);
            __builtin_amdgcn_global_load_lds((glob_f*)(Sb  + (size_t)(k0 + kk) * TX_ + x0 + c),
                                             (lds_f*)(St  + f * 4), 16, 0, 0);
            __builtin_amdgcn_global_load_lds((glob_f*)(MSb + (size_t)(k0 + kk) * TX_ + x0 + c),
                                             (lds_f*)(MSt + f * 4), 16, 0, 0);
        }
        __syncthreads();

#pragma unroll 2
        for (int kk = 0; kk < 16; kk++) {
            float4 z0 = *(const float4*)&Zt[kk * 128 + ty * 4];
            float4 z1 = *(const float4*)&Zt[kk * 128 + 64 + ty * 4];
            float4 s0 = *(const float4*)&St[kk * 128 + tx * 4];
            float4 s1 = *(const float4*)&St[kk * 128 + 64 + tx * 4];
            float4 m0 = *(const float4*)&MSt[kk * 128 + tx * 4];
            float4 m1 = *(const float4*)&MSt[kk * 128 + 64 + tx * 4];
            float4 u0, u1;
            u0.x = -0.5f * z0.x * z0.x; u0.y = -0.5f * z0.y * z0.y;
            u0.z = -0.5f * z0.z * z0.z; u0.w = -0.5f * z0.w * z0.w;
            u1.x = -0.5f * z1.x * z1.x; u1.y = -0.5f * z1.y * z1.y;
            u1.z = -0.5f * z1.z * z1.z; u1.w = -0.5f * z1.w * z1.w;
            float zz[8] = {z0.x, z0.y, z0.z, z0.w, z1.x, z1.y, z1.z, z1.w};
            float uu[8] = {u0.x, u0.y, u0.z, u0.w, u1.x, u1.y, u1.z, u1.w};
            float ss[8] = {s0.x, s0.y, s0.z, s0.w, s1.x, s1.y, s1.z, s1.w};
            float mm[8] = {m0.x, m0.y, m0.z, m0.w, m1.x, m1.y, m1.z, m1.w};
#pragma unroll
            for (int i = 0; i < 8; i++)
#pragma unroll
                for (int j = 0; j < 8; j++)
                    acc[i][j] += uu[i] * ss[j] + zz[i] * mm[j];
        }
        __syncthreads();
    }

    // column constants: sum 6 deterministic partials
    float cv[8] = {0, 0, 0, 0, 0, 0, 0, 0};
#pragma unroll
    for (int p = 0; p < 6; p++) {
        float4 c0 = *(const float4*)&Cpart[(b * 6 + p) * TX_ + x0 + tx * 4];
        float4 c1 = *(const float4*)&Cpart[(b * 6 + p) * TX_ + x0 + 64 + tx * 4];
        cv[0] += c0.x; cv[1] += c0.y; cv[2] += c0.z; cv[3] += c0.w;
        cv[4] += c1.x; cv[5] += c1.y; cv[6] += c1.z; cv[7] += c1.w;
    }

#pragma unroll
    for (int i = 0; i < 8; i++) {
        int y = y0 + ty * 4 + (i & 3) + 64 * (i >> 2);
        float4 o0, o1;
        o0.x = acc[i][0] + cv[0]; o0.y = acc[i][1] + cv[1];
        o0.z = acc[i][2] + cv[2]; o0.w = acc[i][3] + cv[3];
        o1.x = acc[i][4] + cv[4]; o1.y = acc[i][5] + cv[5];
        o1.z = acc[i][6] + cv[6]; o1.w = acc[i][7] + cv[7];
        *(float4*)&NC[((size_t)b * TY_ + y) * TX_ + x0 + tx * 4]      = o0;
        *(float4*)&NC[((size_t)b * TY_ + y) * TX_ + x0 + 64 + tx * 4] = o1;
    }
}

// ============ Kernel C: MAS forward DP — pure VGPR ring, depth 16 ============
// __launch_bounds__(64, 1): 1 wave/EU -> ~512-VGPR budget. Without it the
// scheduler targets default occupancy (~128 VGPR) and sinks the ring loads
// next to their uses (R4: VGPR=136, 358 cy/row = raw load latency per row).
// Early-shfl: v[7] computed first, shfl issued immediately, result consumed
// next row -> DS latency overlaps the j=0..6 updates instead of serializing.
__global__ __launch_bounds__(64, 1) void mas_forward(const float* __restrict__ NC,
                                                     unsigned char* __restrict__ dirs) {
    int b = blockIdx.x;
    int lane = threadIdx.x;
    const float* ncb = NC + (size_t)b * TY_ * TX_;
    const float4* base = (const float4*)ncb + lane * 2;   // row y -> + y*128

    float4 A[16], C[16];
#pragma unroll
    for (int s = 0; s < 16; s++) {
        A[s] = base[(size_t)(1 + s) * 128];
        C[s] = base[(size_t)(1 + s) * 128 + 1];
    }

    float v[8];
#pragma unroll
    for (int j = 0; j < 8; j++) v[j] = NEGV;
    if (lane == 0) v[0] = ncb[0];

    unsigned char* db = dirs + (size_t)b * 2048 * 64 + lane;

    float bound = NEGV;   // pending shfl result: lane-1's v[7] after previous row

    auto row_step = [&](float4 a, float4 c, int y, bool mask) {
        float ncv[8] = {a.x, a.y, a.z, a.w, c.x, c.y, c.z, c.w};
        float vd0 = (lane == 0) ? NEGV : bound;
        // element 7 first: compute, mask, and launch the cross-lane transfer
        float v6o = v[6], v7o = v[7];
        float v7n = ncv[7] + fmaxf(v7o, v6o);
        if (mask && y < 511 && lane * 8 + 7 > y) v7n = NEGV;
        bound = __shfl_up(v7n, 1);               // consumed at next row's vd0
        unsigned bits = (v6o > v7o) ? 0x80u : 0u;
        float vd = vd0;
#pragma unroll
        for (int j = 0; j < 7; j++) {
            float vp = v[j];
            bits |= (vd > vp) ? (1u << j) : 0u;
            v[j] = ncv[j] + fmaxf(vp, vd);
            vd = vp;
        }
        if (mask && y < 511) {
            int xb = lane * 8;
#pragma unroll
            for (int j = 0; j < 7; j++)
                if (xb + j > y) v[j] = NEGV;
        }
        v[7] = v7n;
        db[(size_t)(y - 1) * 64] = (unsigned char)bits;
    };

    int y = 1;
    // masked phase: rows 1..512
    for (int k = 0; k < 32; k++) {
#pragma unroll
        for (int s = 0; s < 16; s++) {
            float4 a = A[s], c = C[s];
            A[s] = base[(size_t)(y + 16) * 128];
            C[s] = base[(size_t)(y + 16) * 128 + 1];
            row_step(a, c, y, true);
            y++;
        }
    }
    // unmasked phase: rows 513..2032
    for (int k = 32; k < 127; k++) {
#pragma unroll
        for (int s = 0; s < 16; s++) {
            float4 a = A[s], c = C[s];
            A[s] = base[(size_t)(y + 16) * 128];
            C[s] = base[(size_t)(y + 16) * 128 + 1];
            row_step(a, c, y, false);
            y++;
        }
    }
    // epilogue: rows 2033..2047 from ring slots 0..14 (no more loads)
#pragma unroll
    for (int s = 0; s < 15; s++) {
        row_step(A[s], C[s], y, false);
        y++;
    }
}

// ============ Kernel D: backtrack (one wave per sample, shfl-windowed) ============
__global__ __launch_bounds__(64, 1) void mas_backtrack(const unsigned* __restrict__ dirs,
                                                       int* __restrict__ path) {
    int b = blockIdx.x;
    int lane = threadIdx.x;
    const unsigned* db = dirs + (size_t)b * 2048 * 16;   // 16 dwords per row
    int idx = TX_ - 1;                                   // path[2047]

    for (int y_hi = 2047; y_hi >= 1; y_hi -= 64) {
        int wb = (idx >> 5) - 2;
        if (wb < 0) wb = 0;
        int base = wb << 5;
        int y = y_hi - lane;
        unsigned w0 = 0, w1 = 0, w2 = 0;
        if (y >= 1) {
            const unsigned* r = db + (size_t)(y - 1) * 16 + wb;
            w0 = r[0]; w1 = r[1]; w2 = r[2];
        }
        int steps = (y_hi < 64) ? y_hi : 64;
        int my_path = 0;
#pragma unroll 8
        for (int t = 0; t < steps; t++) {
            if (lane == t) my_path = idx;
            unsigned u0 = (unsigned)__shfl((int)w0, t);
            unsigned u1 = (unsigned)__shfl((int)w1, t);
            unsigned u2 = (unsigned)__shfl((int)w2, t);
            int off = idx - base;
            unsigned w = (off < 32) ? u0 : ((off < 64) ? u1 : u2);
            idx -= (int)((w >> (off & 31)) & 1u);
        }
        if (lane < steps) path[b * TY_ + (y_hi - lane)] = my_path;
    }
    if (lane == 0) path[b * TY_ + 0] = idx;
}

// ============ Kernel E: durations + l_length ============
__global__ __launch_bounds__(512) void durations_ll(const int* __restrict__ path,
                                                    const float* __restrict__ logw,
                                                    float* __restrict__ out_l) {
    int b = blockIdx.x;
    int tid = threadIdx.x;
    __shared__ int wcnt[TX_];
    __shared__ float partial[8];
    wcnt[tid] = 0;
    __syncthreads();
    for (int y = tid; y < TY_; y += 512)
        atomicAdd(&wcnt[path[b * TY_ + y]], 1);
    __syncthreads();
    float t = logw[b * TX_ + tid] - logf((float)wcnt[tid] + 1e-6f);
    float sq = t * t;
#pragma unroll
    for (int off = 32; off > 0; off >>= 1) sq += __shfl_down(sq, off);
    if ((tid & 63) == 0) partial[tid >> 6] = sq;
    __syncthreads();
    if (tid == 0) {
        float s = 0.f;
#pragma unroll
        for (int i = 0; i < 8; i++) s += partial[i];
        out_l[b] = s;
    }
}

// ============ Kernel F: gather out_main ============
__global__ __launch_bounds__(256) void gather_main(const int* __restrict__ path,
                                                   const float* __restrict__ xm,
                                                   const float* __restrict__ xl,
                                                   float* __restrict__ out) {
    int c = blockIdx.x;      // 0..383
    int b = blockIdx.y;      // 0..15
    int tid = threadIdx.x;
    const float* src = (c < D_) ? (xm + ((size_t)b * D_ + c) * TX_)
                                : (xl + ((size_t)b * D_ + (c - D_)) * TX_);
    const int* pb = path + b * TY_;
    float* ob = out + ((size_t)b * 2 * D_ + c) * TY_;
#pragma unroll
    for (int k = 0; k < 8; k++) {
        int y = tid + k * 256;
        ob[y] = src[pb[y]];
    }
}

// ============ Kernel G: write one-hot attn ============
__global__ __launch_bounds__(128) void write_attn(const int* __restrict__ path,
                                                  float* __restrict__ attn) {
    int blk = blockIdx.x;            // b*2048 + y
    int b = blk >> 11;
    int y = blk & 2047;
    int tid = threadIdx.x;           // covers x in [4*tid, 4*tid+4)
    int p = path[b * TY_ + y];
    float4 val = make_float4(0.f, 0.f, 0.f, 0.f);
    if ((p >> 2) == tid) {
        int r = p & 3;
        if (r == 0) val.x = 1.f;
        else if (r == 1) val.y = 1.f;
        else if (r == 2) val.z = 1.f;
        else val.w = 1.f;
    }
    ((float4*)attn)[((size_t)blk) * 128 + tid] = val;
}

extern "C" void kernel_launch(void* const* d_in, const int* in_sizes, int n_in,
                              void* d_out, int out_size, void* d_ws, size_t ws_size,
                              hipStream_t stream) {
    const float* x_mean = (const float*)d_in[0];
    const float* x_logs = (const float*)d_in[1];
    const float* z      = (const float*)d_in[2];
    const float* logw   = (const float*)d_in[3];
    float* out = (float*)d_out;

    char* ws = (char*)d_ws;
    float* S            = (float*)(ws + 0);
    float* MS           = (float*)(ws + 6291456);
    float* NC           = (float*)(ws + 12615680);
    unsigned char* dirs = (unsigned char*)(ws + 79724544);
    float* Cpart        = (float*)(ws + 79724544);   // aliases dirs; dead before mas_forward
    int* path           = (int*)(ws + 81821696);

    float* out_main = out;                 // [B,384,TY]
    float* out_l    = out + 12582912;      // [B]
    float* out_attn = out + 12582928;      // [B,TY,TX]

    precomp<<<dim3(B_, 6), dim3(512), 0, stream>>>(x_mean, x_logs, S, MS, Cpart);
    gemm_nc<<<dim3(4, 16, 16), dim3(256), 0, stream>>>(z, S, MS, Cpart, NC);
    mas_forward<<<dim3(B_), dim3(64), 0, stream>>>(NC, dirs);
    mas_backtrack<<<dim3(B_), dim3(64), 0, stream>>>((const unsigned*)dirs, path);
    durations_ll<<<dim3(B_), dim3(512), 0, stream>>>(path, logw, out_l);
    gather_main<<<dim3(384, 16), dim3(256), 0, stream>>>(path, x_mean, x_logs, out_main);
    write_attn<<<dim3(B_ * TY_), dim3(128), 0, stream>>>(path, out_attn);
}